// Round 3
// baseline (2565.354 us; speedup 1.0000x reference)
//
#include <hip/hip_runtime.h>

#define T_SEQ 512
#define U_TAGS 128
#define D_DIM 1024

// ---------------------------------------------------------------------------
// Cross-lane helpers (unchanged from round-0 proven kernel).
// ---------------------------------------------------------------------------
__device__ __forceinline__ float rl_f(float v, int lane) {
  return __int_as_float(__builtin_amdgcn_readlane(__float_as_int(v), lane));
}
template <int CTRL>
__device__ __forceinline__ float dpp_max_step(float x) {
  int v = __float_as_int(x);
  int t = __builtin_amdgcn_update_dpp(v, v, CTRL, 0xF, 0xF, false);
  return fmaxf(x, __int_as_float(t));
}
__device__ __forceinline__ float wave_max64_bcast(float x) {
  x = dpp_max_step<0x111>(x);  // row_shr:1
  x = dpp_max_step<0x112>(x);  // row_shr:2
  x = dpp_max_step<0x114>(x);  // row_shr:4
  x = dpp_max_step<0x118>(x);  // row_shr:8
  x = dpp_max_step<0x142>(x);  // row_bcast:15
  x = dpp_max_step<0x143>(x);  // row_bcast:31
  return rl_f(x, 63);
}
__device__ __forceinline__ void win(float sa, int ia, float sb, int ib,
                                    float& so, int& io) {
  bool g = sa >= sb;
  so = g ? sa : sb;
  io = g ? ia : ib;
}

// ---------------------------------------------------------------------------
// Single fully-fused kernel. One block per batch, 512 threads (8 waves).
//   wave 0        : pruned Viterbi forward recurrence (LDS-only), setprio 1
//   waves 1..4    : GEMM producers. Per 8-step chunk, wave w=(kh,jh) computes
//                   logits[t, j] partial over K-half kh for col-half jh,
//                   8 rows per thread (B row read ONCE per chunk -> L2-bound
//                   3.8us/chunk, hidden under the 5.1us/chunk recurrence).
//                   kh0 writes partial to ring slot; kh1 adds its partial +
//                   bias (+lb/rb) -> bitwise-identical logits to the proven
//                   round-0 kernel ((p0+p1)+bias, k ascending per half).
//   waves 5..7    : park at the post-forward barrier.
// All synchronization is block-local LDS initialized at block start:
// replay-safe (rocprof re-executes a dispatch standalone), no atomics, no
// device globals, no workspace, no cross-block dependencies of any kind.
// ---------------------------------------------------------------------------
__global__ __launch_bounds__(512) void crf_all(
    const float* __restrict__ x,      // [64, 512, 1024]
    const float* __restrict__ Bk,     // [1024, 128]
    const float* __restrict__ bias,   // [128]
    const float* __restrict__ lb, const float* __restrict__ rb,  // [128]
    const float* __restrict__ trans,  // [128, 128]
    float* __restrict__ out) {        // [64, 512] fp32 tags
  __shared__ __align__(16) float trs[U_TAGS * U_TAGS];              // 64 KB
  __shared__ __align__(16) float ring[4 * 8 * U_TAGS];              // 16 KB
  __shared__ __align__(16) unsigned char bp[(T_SEQ - 1) * U_TAGS];  // 65408 B
  // flags: [0]=chunks consumed (wave0); [1],[2]=kh0 jh0/jh1 chunks written;
  //        [3],[4]=kh1 jh0/jh1 chunks finalized. Single writer each.
  __shared__ int flags[8];
  __shared__ unsigned char tags[T_SEQ];
  __shared__ unsigned char M[8][U_TAGS];
  __shared__ unsigned char seedE[8];
  __shared__ float rmaxs[U_TAGS];
  __shared__ float wmin2[2];
  __shared__ float gminS;
  __shared__ int lastTagS;

  const int b = blockIdx.x;
  const int tid = threadIdx.x;

  // Stage trans (coalesced), 8 float4 per thread (512 threads).
#pragma unroll
  for (int it = 0; it < 8; ++it)
    *(float4*)&trs[(it * 512 + tid) * 4] =
        *(const float4*)&trans[(it * 512 + tid) * 4];
  if (tid < 8) flags[tid] = 0;
  __syncthreads();

  // rmaxs[i] = max_j trs[i][j]; gmin = min over all trans.
  float rowmin = 1e30f;
  if (tid < U_TAGS) {
    float mx = -1e30f, mn = 1e30f;
    for (int q = 0; q < 32; ++q) {
      float4 v = *(const float4*)&trs[tid * U_TAGS + q * 4];
      mx = fmaxf(fmaxf(mx, v.x), fmaxf(v.y, fmaxf(v.z, v.w)));
      mn = fminf(fminf(mn, v.x), fminf(v.y, fminf(v.z, v.w)));
    }
    rmaxs[tid] = mx;
    rowmin = mn;
#pragma unroll
    for (int off = 1; off < 64; off <<= 1)
      rowmin = fminf(rowmin, __shfl_xor(rowmin, off));
    if ((tid & 63) == 0) wmin2[tid >> 6] = rowmin;
  }
  __syncthreads();
  if (tid == 0) gminS = fminf(wmin2[0], wmin2[1]);
  __syncthreads();

  const int wv = tid >> 6, l = tid & 63;
  volatile int* vfl = (volatile int*)flags;

  if (wv >= 1 && wv <= 4) {
    // ================= GEMM producer =================
    const int kh = (wv - 1) >> 1;  // K-half: 0 -> k in [0,512), 1 -> [512,1024)
    const int jh = (wv - 1) & 1;   // column half
    const int j = jh * 64 + l;
    const float* Abase = x + (size_t)b * T_SEQ * D_DIM + kh * (D_DIM / 2);
    const float* Bbase = Bk + (size_t)(kh * (D_DIM / 2)) * U_TAGS + j;
    const float bj = bias[j];
    const float lbj = lb[j];
    const float rbj = rb[j];

    for (int c = 0; c < 64; ++c) {
      while (vfl[0] + 4 <= c) {}  // ring credit: slot free once consumer moved on
      const float* Arow = Abase + (size_t)(c * 8) * D_DIM;
      float acc0 = 0.f, acc1 = 0.f, acc2 = 0.f, acc3 = 0.f;
      float acc4 = 0.f, acc5 = 0.f, acc6 = 0.f, acc7 = 0.f;
      const float* Bp = Bbase;
      for (int k4 = 0; k4 < D_DIM / 8; ++k4) {  // 128 iters x 4 k
        // A values are wave-uniform (all lanes same address -> broadcast).
        const float4 a0 = *(const float4*)&Arow[0 * D_DIM + k4 * 4];
        const float4 a1 = *(const float4*)&Arow[1 * D_DIM + k4 * 4];
        const float4 a2 = *(const float4*)&Arow[2 * D_DIM + k4 * 4];
        const float4 a3 = *(const float4*)&Arow[3 * D_DIM + k4 * 4];
        const float4 a4 = *(const float4*)&Arow[4 * D_DIM + k4 * 4];
        const float4 a5 = *(const float4*)&Arow[5 * D_DIM + k4 * 4];
        const float4 a6 = *(const float4*)&Arow[6 * D_DIM + k4 * 4];
        const float4 a7 = *(const float4*)&Arow[7 * D_DIM + k4 * 4];
        const float b0 = Bp[0];
        const float b1 = Bp[U_TAGS];
        const float b2 = Bp[2 * U_TAGS];
        const float b3 = Bp[3 * U_TAGS];
        acc0 = fmaf(a0.x, b0, acc0); acc1 = fmaf(a1.x, b0, acc1);
        acc2 = fmaf(a2.x, b0, acc2); acc3 = fmaf(a3.x, b0, acc3);
        acc4 = fmaf(a4.x, b0, acc4); acc5 = fmaf(a5.x, b0, acc5);
        acc6 = fmaf(a6.x, b0, acc6); acc7 = fmaf(a7.x, b0, acc7);
        acc0 = fmaf(a0.y, b1, acc0); acc1 = fmaf(a1.y, b1, acc1);
        acc2 = fmaf(a2.y, b1, acc2); acc3 = fmaf(a3.y, b1, acc3);
        acc4 = fmaf(a4.y, b1, acc4); acc5 = fmaf(a5.y, b1, acc5);
        acc6 = fmaf(a6.y, b1, acc6); acc7 = fmaf(a7.y, b1, acc7);
        acc0 = fmaf(a0.z, b2, acc0); acc1 = fmaf(a1.z, b2, acc1);
        acc2 = fmaf(a2.z, b2, acc2); acc3 = fmaf(a3.z, b2, acc3);
        acc4 = fmaf(a4.z, b2, acc4); acc5 = fmaf(a5.z, b2, acc5);
        acc6 = fmaf(a6.z, b2, acc6); acc7 = fmaf(a7.z, b2, acc7);
        acc0 = fmaf(a0.w, b3, acc0); acc1 = fmaf(a1.w, b3, acc1);
        acc2 = fmaf(a2.w, b3, acc2); acc3 = fmaf(a3.w, b3, acc3);
        acc4 = fmaf(a4.w, b3, acc4); acc5 = fmaf(a5.w, b3, acc5);
        acc6 = fmaf(a6.w, b3, acc6); acc7 = fmaf(a7.w, b3, acc7);
        Bp += 4 * U_TAGS;
      }

      float* rslot = ring + (c & 3) * 1024 + j;
      if (kh == 0) {
        rslot[0 * U_TAGS] = acc0; rslot[1 * U_TAGS] = acc1;
        rslot[2 * U_TAGS] = acc2; rslot[3 * U_TAGS] = acc3;
        rslot[4 * U_TAGS] = acc4; rslot[5 * U_TAGS] = acc5;
        rslot[6 * U_TAGS] = acc6; rslot[7 * U_TAGS] = acc7;
        __threadfence_block();
        if (l == 0) vfl[1 + jh] = c + 1;
      } else {
        while (vfl[1 + jh] < c + 1) {}  // wait matching kh0 col-half
        const int t0 = c * 8;
        float o0 = rslot[0 * U_TAGS] + acc0 + bj;
        float o1 = rslot[1 * U_TAGS] + acc1 + bj;
        float o2 = rslot[2 * U_TAGS] + acc2 + bj;
        float o3 = rslot[3 * U_TAGS] + acc3 + bj;
        float o4 = rslot[4 * U_TAGS] + acc4 + bj;
        float o5 = rslot[5 * U_TAGS] + acc5 + bj;
        float o6 = rslot[6 * U_TAGS] + acc6 + bj;
        float o7 = rslot[7 * U_TAGS] + acc7 + bj;
        if (t0 == 0) o0 += lbj;                    // t == 0
        if (t0 + 7 == T_SEQ - 1) o7 += rbj;        // t == 511
        rslot[0 * U_TAGS] = o0; rslot[1 * U_TAGS] = o1;
        rslot[2 * U_TAGS] = o2; rslot[3 * U_TAGS] = o3;
        rslot[4 * U_TAGS] = o4; rslot[5 * U_TAGS] = o5;
        rslot[6 * U_TAGS] = o6; rslot[7 * U_TAGS] = o7;
        __threadfence_block();
        if (l == 0) vfl[3 + jh] = c + 1;
      }
    }
  } else if (wv == 0) {
    // ================= consumer: pruned forward recurrence =================
    __builtin_amdgcn_s_setprio(1);  // latency-critical chain; producers at 0
    const float cc0 = rmaxs[l] - gminS + 0.01f;
    const float cc1 = rmaxs[64 + l] - gminS + 0.01f;
    while (vfl[3] < 1 || vfl[4] < 1) {}
    float v0 = ring[l];
    float v1 = ring[64 + l];
    const unsigned long long G = 0x8000000000000000ull;
    int bpoff = l;

    for (int t = 1; t < T_SEQ; ++t) {
      if ((t & 7) == 0) {
        const int c = t >> 3;
        if (l == 0) vfl[0] = c;  // chunks < c fully consumed
        while (vfl[3] <= c || vfl[4] <= c) {}
      }
      const float* sl = ring + ((t >> 3) & 3) * 1024 + (t & 7) * U_TAGS;
      float lg0 = sl[l];
      float lg1 = sl[64 + l];

      const float vm = wave_max64_bcast(fmaxf(v0, v1));
      unsigned long long m0 = __ballot(v0 + cc0 >= vm);
      unsigned long long m1 = __ballot(v1 + cc1 >= vm);

      unsigned long long rA1 = m0 & (m0 - 1), rA2 = rA1 & (rA1 - 1);
      unsigned long long rB1 = m1 & (m1 - 1), rB2 = rB1 & (rB1 - 1);
      const int iA0 = __builtin_ctzll(m0 | G);
      const int iA1 = __builtin_ctzll(rA1 | G);
      const int iA2 = __builtin_ctzll(rA2 | G);
      const int iB0 = __builtin_ctzll(m1 | G);
      const int iB1 = __builtin_ctzll(rB1 | G);
      const int iB2 = __builtin_ctzll(rB2 | G);
      unsigned long long tail = (rA2 & (rA2 - 1)) | (rB2 & (rB2 - 1));

      const float svA0 = rl_f(v0, iA0), svA1 = rl_f(v0, iA1),
                  svA2 = rl_f(v0, iA2);
      const float svB0 = rl_f(v1, iB0), svB1 = rl_f(v1, iB1),
                  svB2 = rl_f(v1, iB2);

      const float* pA0 = &trs[iA0 * U_TAGS + l];
      const float* pA1 = &trs[iA1 * U_TAGS + l];
      const float* pA2 = &trs[iA2 * U_TAGS + l];
      const float* pB0 = &trs[(64 + iB0) * U_TAGS + l];
      const float* pB1 = &trs[(64 + iB1) * U_TAGS + l];
      const float* pB2 = &trs[(64 + iB2) * U_TAGS + l];
      const float tA0L = pA0[0], tA0H = pA0[64];
      const float tA1L = pA1[0], tA1H = pA1[64];
      const float tA2L = pA2[0], tA2H = pA2[64];
      const float tB0L = pB0[0], tB0H = pB0[64];
      const float tB1L = pB1[0], tB1H = pB1[64];
      const float tB2L = pB2[0], tB2H = pB2[64];

      float wa, wb, wL; int xa, xb, xL;
      win(svA0 + tA0L, iA0, svA1 + tA1L, iA1, wa, xa);
      win(wa, xa, svA2 + tA2L, iA2, wa, xa);
      win(svB0 + tB0L, 64 + iB0, svB1 + tB1L, 64 + iB1, wb, xb);
      win(wb, xb, svB2 + tB2L, 64 + iB2, wb, xb);
      win(wa, xa, wb, xb, wL, xL);
      float wH; int xH;
      win(svA0 + tA0H, iA0, svA1 + tA1H, iA1, wa, xa);
      win(wa, xa, svA2 + tA2H, iA2, wa, xa);
      win(svB0 + tB0H, 64 + iB0, svB1 + tB1H, 64 + iB1, wb, xb);
      win(wb, xb, svB2 + tB2H, 64 + iB2, wb, xb);
      win(wa, xa, wb, xb, wH, xH);

      if (tail) {  // rare: >3 candidates in a half, tie-aware
        unsigned long long rr = rA2 & (rA2 - 1);
        while (rr) {
          int i = __builtin_ctzll(rr); rr &= rr - 1;
          float vi = rl_f(v0, i);
          float sL = vi + trs[i * U_TAGS + l];
          float sH = vi + trs[i * U_TAGS + 64 + l];
          if (sL > wL || (sL == wL && i < xL)) { wL = sL; xL = i; }
          if (sH > wH || (sH == wH && i < xH)) { wH = sH; xH = i; }
        }
        rr = rB2 & (rB2 - 1);
        while (rr) {
          int i = __builtin_ctzll(rr); rr &= rr - 1;
          float vi = rl_f(v1, i);
          float sL = vi + trs[(64 + i) * U_TAGS + l];
          float sH = vi + trs[(64 + i) * U_TAGS + 64 + l];
          if (sL > wL || (sL == wL && 64 + i < xL)) { wL = sL; xL = 64 + i; }
          if (sH > wH || (sH == wH && 64 + i < xH)) { wH = sH; xH = 64 + i; }
        }
      }

      bp[bpoff] = (unsigned char)xL;
      bp[bpoff + 64] = (unsigned char)xH;
      bpoff += U_TAGS;
      v0 = wL + lg0;  // same fp32 ops as reference
      v1 = wH + lg1;
    }

    // final argmax (first max over j=0..127)
    float val = v0; int idx = l;
    if (v1 > v0) { val = v1; idx = 64 + l; }
#pragma unroll
    for (int off = 1; off < 64; off <<= 1) {
      float vo = __shfl_xor(val, off);
      int io = __shfl_xor(idx, off);
      if (vo > val || (vo == val && io < idx)) { val = vo; idx = io; }
    }
    if (l == 0) { lastTagS = idx; tags[T_SEQ - 1] = (unsigned char)idx; }
    __builtin_amdgcn_s_setprio(0);
  }
  __syncthreads();  // waves 5-7 waited here during the forward pass

  // Backtrack pass A: 1024 chains (8 chunks x 128 seeds), 2 per thread.
#pragma unroll
  for (int qq = 0; qq < 2; ++qq) {
    const int chain = tid + qq * 512;
    const int c = chain >> 7, s = chain & 127;
    const int lo = c * 64;
    const int hi = (c == 7) ? (T_SEQ - 2) : (c * 64 + 63);
    int cur = s;
    for (int t = hi; t >= lo; --t) cur = bp[t * U_TAGS + cur];
    M[c][s] = (unsigned char)cur;
  }
  __syncthreads();
  if (tid == 0) {
    int e = lastTagS;
    seedE[7] = (unsigned char)e;
    for (int c = 7; c >= 1; --c) { e = M[c][e]; seedE[c - 1] = (unsigned char)e; }
  }
  __syncthreads();
  if (tid < 8) {
    const int c = tid;
    const int lo = c * 64;
    const int hi = (c == 7) ? (T_SEQ - 2) : (c * 64 + 63);
    int cur = seedE[c];
    for (int t = hi; t >= lo; --t) {
      cur = bp[t * U_TAGS + cur];
      tags[t] = (unsigned char)cur;
    }
  }
  __syncthreads();
  out[(size_t)b * T_SEQ + tid] = (float)tags[tid];
}

// ---------------------------------------------------------------------------
extern "C" void kernel_launch(void* const* d_in, const int* in_sizes, int n_in,
                              void* d_out, int out_size, void* d_ws,
                              size_t ws_size, hipStream_t stream) {
  const float* x = (const float*)d_in[0];
  const float* kern = (const float*)d_in[1];
  const float* bias = (const float*)d_in[2];
  const float* chain = (const float*)d_in[3];
  const float* lb = (const float*)d_in[4];
  const float* rb = (const float*)d_in[5];
  float* out = (float*)d_out;
  (void)d_ws; (void)ws_size;  // no workspace needed: logits never leave LDS

  crf_all<<<64, 512, 0, stream>>>(x, kern, bias, lb, rb, chain, out);
}

// Round 4
// 1804.878 us; speedup vs baseline: 1.4213x; 1.4213x over previous
//
#include <hip/hip_runtime.h>

#define T_SEQ 512
#define U_TAGS 128
#define D_DIM 1024

typedef float __attribute__((ext_vector_type(2))) f32x2;
typedef float __attribute__((ext_vector_type(4))) f32x4;

// ---------------------------------------------------------------------------
// Cross-lane helpers (unchanged from proven kernel).
// ---------------------------------------------------------------------------
__device__ __forceinline__ float rl_f(float v, int lane) {
  return __int_as_float(__builtin_amdgcn_readlane(__float_as_int(v), lane));
}
template <int CTRL>
__device__ __forceinline__ float dpp_max_step(float x) {
  int v = __float_as_int(x);
  int t = __builtin_amdgcn_update_dpp(v, v, CTRL, 0xF, 0xF, false);
  return fmaxf(x, __int_as_float(t));
}
__device__ __forceinline__ float wave_max64_bcast(float x) {
  x = dpp_max_step<0x111>(x);  // row_shr:1
  x = dpp_max_step<0x112>(x);  // row_shr:2
  x = dpp_max_step<0x114>(x);  // row_shr:4
  x = dpp_max_step<0x118>(x);  // row_shr:8
  x = dpp_max_step<0x142>(x);  // row_bcast:15
  x = dpp_max_step<0x143>(x);  // row_bcast:31
  return rl_f(x, 63);
}
__device__ __forceinline__ void win(float sa, int ia, float sb, int ib,
                                    float& so, int& io) {
  bool g = sa >= sb;
  so = g ? sa : sb;
  io = g ? ia : ib;
}

// Packed FP32 FMA. a is a register pair {A[k],A[k+1]}; op_sel broadcasts one
// half of a to BOTH result lanes (no v_mov needed). b = {B[k][2l],B[k][2l+1]}.
//   pk_lo: d.lo += a.lo*b.lo ; d.hi += a.lo*b.hi   (k   contribution)
//   pk_hi: d.lo += a.hi*b.lo ; d.hi += a.hi*b.hi   (k+1 contribution)
__device__ __forceinline__ void pk_lo(f32x2& d, f32x2 a, f32x2 b) {
  asm("v_pk_fma_f32 %0, %1, %2, %0 op_sel:[0,0,0] op_sel_hi:[0,1,1]"
      : "+v"(d)
      : "v"(a), "v"(b));
}
__device__ __forceinline__ void pk_hi(f32x2& d, f32x2 a, f32x2 b) {
  asm("v_pk_fma_f32 %0, %1, %2, %0 op_sel:[1,0,0] op_sel_hi:[1,1,1]"
      : "+v"(d)
      : "v"(a), "v"(b));
}

// One software-pipeline group: 8 rows x 4 k of A (uniform) + 4 k of B pairs.
struct Grp {
  f32x4 a0, a1, a2, a3, a4, a5, a6, a7;
  f32x2 b0, b1, b2, b3;
};

#define LOADG(g, i)                                   \
  do {                                                \
    const float* Ap_ = Aq + (i) * 4;                  \
    g.a0 = *(const f32x4*)(Ap_ + 0 * D_DIM);          \
    g.a1 = *(const f32x4*)(Ap_ + 1 * D_DIM);          \
    g.a2 = *(const f32x4*)(Ap_ + 2 * D_DIM);          \
    g.a3 = *(const f32x4*)(Ap_ + 3 * D_DIM);          \
    g.a4 = *(const f32x4*)(Ap_ + 4 * D_DIM);          \
    g.a5 = *(const f32x4*)(Ap_ + 5 * D_DIM);          \
    g.a6 = *(const f32x4*)(Ap_ + 6 * D_DIM);          \
    g.a7 = *(const f32x4*)(Ap_ + 7 * D_DIM);          \
    const float* Bp_ = Bq + (size_t)(i) * 4 * U_TAGS; \
    g.b0 = *(const f32x2*)(Bp_ + 0 * U_TAGS);         \
    g.b1 = *(const f32x2*)(Bp_ + 1 * U_TAGS);         \
    g.b2 = *(const f32x2*)(Bp_ + 2 * U_TAGS);         \
    g.b3 = *(const f32x2*)(Bp_ + 3 * U_TAGS);         \
  } while (0)

#define COMPG(g)                                                       \
  do {                                                                 \
    pk_lo(acc0, g.a0.xy, g.b0); pk_hi(acc0, g.a0.xy, g.b1);            \
    pk_lo(acc0, g.a0.zw, g.b2); pk_hi(acc0, g.a0.zw, g.b3);            \
    pk_lo(acc1, g.a1.xy, g.b0); pk_hi(acc1, g.a1.xy, g.b1);            \
    pk_lo(acc1, g.a1.zw, g.b2); pk_hi(acc1, g.a1.zw, g.b3);            \
    pk_lo(acc2, g.a2.xy, g.b0); pk_hi(acc2, g.a2.xy, g.b1);            \
    pk_lo(acc2, g.a2.zw, g.b2); pk_hi(acc2, g.a2.zw, g.b3);            \
    pk_lo(acc3, g.a3.xy, g.b0); pk_hi(acc3, g.a3.xy, g.b1);            \
    pk_lo(acc3, g.a3.zw, g.b2); pk_hi(acc3, g.a3.zw, g.b3);            \
    pk_lo(acc4, g.a4.xy, g.b0); pk_hi(acc4, g.a4.xy, g.b1);            \
    pk_lo(acc4, g.a4.zw, g.b2); pk_hi(acc4, g.a4.zw, g.b3);            \
    pk_lo(acc5, g.a5.xy, g.b0); pk_hi(acc5, g.a5.xy, g.b1);            \
    pk_lo(acc5, g.a5.zw, g.b2); pk_hi(acc5, g.a5.zw, g.b3);            \
    pk_lo(acc6, g.a6.xy, g.b0); pk_hi(acc6, g.a6.xy, g.b1);            \
    pk_lo(acc6, g.a6.zw, g.b2); pk_hi(acc6, g.a6.zw, g.b3);            \
    pk_lo(acc7, g.a7.xy, g.b0); pk_hi(acc7, g.a7.xy, g.b1);            \
    pk_lo(acc7, g.a7.zw, g.b2); pk_hi(acc7, g.a7.zw, g.b3);            \
  } while (0)

// ---------------------------------------------------------------------------
// Single fully-fused kernel. One block per batch, 512 threads (8 waves):
//   wave 0     : pruned Viterbi forward recurrence (LDS-only), setprio 1
//   waves 1..4 : GEMM producers, K-quarter q = wv-1. Each covers ALL 128
//                cols (lane owns adjacent pair 2l,2l+1) x 8 rows via
//                v_pk_fma_f32; modulo-4 register pipeline (distance 2).
//                Partials combined by a q0->q1->q2->q3 add chain in the
//                ring slot; q3 adds bias (+lb/rb) and publishes the chunk.
//   waves 5..7 : A-prefetchers, streaming chunk A-regions ~6 chunks ahead
//                (gated on consumed counter) so producers hit L2 not HBM.
// All sync is block-local LDS, zeroed at block start, chunk-id-tagged flags
// (single writer each): replay-safe, no atomics, no globals, no workspace.
// ---------------------------------------------------------------------------
__global__ __launch_bounds__(512) void crf_all(
    const float* __restrict__ x,      // [64, 512, 1024]
    const float* __restrict__ Bk,     // [1024, 128]
    const float* __restrict__ bias,   // [128]
    const float* __restrict__ lb, const float* __restrict__ rb,  // [128]
    const float* __restrict__ trans,  // [128, 128]
    float* __restrict__ out) {        // [64, 512] fp32 tags
  __shared__ __align__(16) float trs[U_TAGS * U_TAGS];              // 64 KB
  __shared__ __align__(16) float ring[4 * 8 * U_TAGS];              // 16 KB
  __shared__ __align__(16) unsigned char bp[(T_SEQ - 1) * U_TAGS];  // 65408 B
  __shared__ int sF[4][4];   // [quarter][slot] = chunk+1 committed
  __shared__ int flags[4];   // [0] = chunks fully consumed by wave 0
  __shared__ unsigned char tags[T_SEQ];
  __shared__ unsigned char M[8][U_TAGS];
  __shared__ unsigned char seedE[8];
  __shared__ float rmaxs[U_TAGS];
  __shared__ float wmin2[2];
  __shared__ float gminS;
  __shared__ int lastTagS;

  const int b = blockIdx.x;
  const int tid = threadIdx.x;

  // Stage trans (coalesced), 8 float4 per thread (512 threads).
#pragma unroll
  for (int it = 0; it < 8; ++it)
    *(f32x4*)&trs[(it * 512 + tid) * 4] =
        *(const f32x4*)&trans[(it * 512 + tid) * 4];
  if (tid < 16) ((int*)sF)[tid] = 0;
  if (tid == 16) flags[0] = 0;
  __syncthreads();

  // rmaxs[i] = max_j trs[i][j]; gmin = min over all trans.
  float rowmin = 1e30f;
  if (tid < U_TAGS) {
    float mx = -1e30f, mn = 1e30f;
    for (int q = 0; q < 32; ++q) {
      f32x4 v = *(const f32x4*)&trs[tid * U_TAGS + q * 4];
      mx = fmaxf(fmaxf(mx, v.x), fmaxf(v.y, fmaxf(v.z, v.w)));
      mn = fminf(fminf(mn, v.x), fminf(v.y, fminf(v.z, v.w)));
    }
    rmaxs[tid] = mx;
    rowmin = mn;
#pragma unroll
    for (int off = 1; off < 64; off <<= 1)
      rowmin = fminf(rowmin, __shfl_xor(rowmin, off));
    if ((tid & 63) == 0) wmin2[tid >> 6] = rowmin;
  }
  __syncthreads();
  if (tid == 0) gminS = fminf(wmin2[0], wmin2[1]);
  __syncthreads();

  const int wv = tid >> 6, l = tid & 63;
  volatile int* vfl = (volatile int*)flags;
  volatile int(*vSF)[4] = (volatile int(*)[4])sF;

  if (wv >= 1 && wv <= 4) {
    // ================= GEMM producer (K-quarter q) =================
    const int q = wv - 1;
    const float* Bq = Bk + (size_t)q * 256 * U_TAGS + 2 * l;
    const f32x2 bias2 = *(const f32x2*)&bias[2 * l];
    const f32x2 lb2 = *(const f32x2*)&lb[2 * l];
    const f32x2 rb2 = *(const f32x2*)&rb[2 * l];

    for (int c = 0; c < 64; ++c) {
      if (q == 0)
        while (vfl[0] < c - 3) __builtin_amdgcn_s_sleep(1);  // ring credit
      const float* Aq = x + ((size_t)b * T_SEQ + c * 8) * D_DIM + q * 256;
      f32x2 acc0 = {0.f, 0.f}, acc1 = {0.f, 0.f}, acc2 = {0.f, 0.f},
            acc3 = {0.f, 0.f}, acc4 = {0.f, 0.f}, acc5 = {0.f, 0.f},
            acc6 = {0.f, 0.f}, acc7 = {0.f, 0.f};
      Grp g0, g1, g2, g3;
      LOADG(g0, 0);
      LOADG(g1, 1);
#pragma unroll 1
      for (int i = 0; i < 60; i += 4) {  // 15 trips; groups 0..59 + epilogue
        LOADG(g2, i + 2); COMPG(g0);
        LOADG(g3, i + 3); COMPG(g1);
        LOADG(g0, i + 4); COMPG(g2);
        LOADG(g1, i + 5); COMPG(g3);
      }
      LOADG(g2, 62); COMPG(g0);  // group 60
      LOADG(g3, 63); COMPG(g1);  // group 61
      COMPG(g2);                 // group 62
      COMPG(g3);                 // group 63

      // ---- combine chain in ring slot ----
      f32x2* r2 = (f32x2*)(ring + (c & 3) * 1024) + l;  // + r*64 per row
      if (q == 0) {
        r2[0 * 64] = acc0; r2[1 * 64] = acc1; r2[2 * 64] = acc2;
        r2[3 * 64] = acc3; r2[4 * 64] = acc4; r2[5 * 64] = acc5;
        r2[6 * 64] = acc6; r2[7 * 64] = acc7;
        __threadfence_block();
        if (l == 0) vSF[0][c & 3] = c + 1;
      } else {
        while (vSF[q - 1][c & 3] != c + 1) __builtin_amdgcn_s_sleep(1);
        if (q < 3) {
          r2[0 * 64] += acc0; r2[1 * 64] += acc1; r2[2 * 64] += acc2;
          r2[3 * 64] += acc3; r2[4 * 64] += acc4; r2[5 * 64] += acc5;
          r2[6 * 64] += acc6; r2[7 * 64] += acc7;
          __threadfence_block();
          if (l == 0) vSF[q][c & 3] = c + 1;
        } else {
          f32x2 o0 = r2[0 * 64] + acc0 + bias2;
          f32x2 o1 = r2[1 * 64] + acc1 + bias2;
          f32x2 o2 = r2[2 * 64] + acc2 + bias2;
          f32x2 o3 = r2[3 * 64] + acc3 + bias2;
          f32x2 o4 = r2[4 * 64] + acc4 + bias2;
          f32x2 o5 = r2[5 * 64] + acc5 + bias2;
          f32x2 o6 = r2[6 * 64] + acc6 + bias2;
          f32x2 o7 = r2[7 * 64] + acc7 + bias2;
          if (c == 0) o0 += lb2;        // t == 0
          if (c == 63) o7 += rb2;       // t == 511
          r2[0 * 64] = o0; r2[1 * 64] = o1; r2[2 * 64] = o2;
          r2[3 * 64] = o3; r2[4 * 64] = o4; r2[5 * 64] = o5;
          r2[6 * 64] = o6; r2[7 * 64] = o7;
          __threadfence_block();
          if (l == 0) vSF[3][c & 3] = c + 1;
        }
      }
    }
  } else if (wv == 0) {
    // ================= consumer: pruned forward recurrence =================
    __builtin_amdgcn_s_setprio(1);  // latency-critical chain
    const float cc0 = rmaxs[l] - gminS + 0.01f;
    const float cc1 = rmaxs[64 + l] - gminS + 0.01f;
    while (vSF[3][0] != 1) __builtin_amdgcn_s_sleep(1);
    float v0 = ring[l];
    float v1 = ring[64 + l];
    const unsigned long long G = 0x8000000000000000ull;
    int bpoff = l;

    for (int t = 1; t < T_SEQ; ++t) {
      if ((t & 7) == 0) {
        const int c = t >> 3;
        if (l == 0) vfl[0] = c;  // chunks < c fully consumed
        while (vSF[3][c & 3] != c + 1) __builtin_amdgcn_s_sleep(1);
      }
      const float* sl = ring + ((t >> 3) & 3) * 1024 + (t & 7) * U_TAGS;
      float lg0 = sl[l];
      float lg1 = sl[64 + l];

      const float vm = wave_max64_bcast(fmaxf(v0, v1));
      unsigned long long m0 = __ballot(v0 + cc0 >= vm);
      unsigned long long m1 = __ballot(v1 + cc1 >= vm);

      unsigned long long rA1 = m0 & (m0 - 1), rA2 = rA1 & (rA1 - 1);
      unsigned long long rB1 = m1 & (m1 - 1), rB2 = rB1 & (rB1 - 1);
      const int iA0 = __builtin_ctzll(m0 | G);
      const int iA1 = __builtin_ctzll(rA1 | G);
      const int iA2 = __builtin_ctzll(rA2 | G);
      const int iB0 = __builtin_ctzll(m1 | G);
      const int iB1 = __builtin_ctzll(rB1 | G);
      const int iB2 = __builtin_ctzll(rB2 | G);
      unsigned long long tail = (rA2 & (rA2 - 1)) | (rB2 & (rB2 - 1));

      const float svA0 = rl_f(v0, iA0), svA1 = rl_f(v0, iA1),
                  svA2 = rl_f(v0, iA2);
      const float svB0 = rl_f(v1, iB0), svB1 = rl_f(v1, iB1),
                  svB2 = rl_f(v1, iB2);

      const float* pA0 = &trs[iA0 * U_TAGS + l];
      const float* pA1 = &trs[iA1 * U_TAGS + l];
      const float* pA2 = &trs[iA2 * U_TAGS + l];
      const float* pB0 = &trs[(64 + iB0) * U_TAGS + l];
      const float* pB1 = &trs[(64 + iB1) * U_TAGS + l];
      const float* pB2 = &trs[(64 + iB2) * U_TAGS + l];
      const float tA0L = pA0[0], tA0H = pA0[64];
      const float tA1L = pA1[0], tA1H = pA1[64];
      const float tA2L = pA2[0], tA2H = pA2[64];
      const float tB0L = pB0[0], tB0H = pB0[64];
      const float tB1L = pB1[0], tB1H = pB1[64];
      const float tB2L = pB2[0], tB2H = pB2[64];

      float wa, wb, wL; int xa, xb, xL;
      win(svA0 + tA0L, iA0, svA1 + tA1L, iA1, wa, xa);
      win(wa, xa, svA2 + tA2L, iA2, wa, xa);
      win(svB0 + tB0L, 64 + iB0, svB1 + tB1L, 64 + iB1, wb, xb);
      win(wb, xb, svB2 + tB2L, 64 + iB2, wb, xb);
      win(wa, xa, wb, xb, wL, xL);
      float wH; int xH;
      win(svA0 + tA0H, iA0, svA1 + tA1H, iA1, wa, xa);
      win(wa, xa, svA2 + tA2H, iA2, wa, xa);
      win(svB0 + tB0H, 64 + iB0, svB1 + tB1H, 64 + iB1, wb, xb);
      win(wb, xb, svB2 + tB2H, 64 + iB2, wb, xb);
      win(wa, xa, wb, xb, wH, xH);

      if (tail) {  // rare: >3 candidates in a half, tie-aware
        unsigned long long rr = rA2 & (rA2 - 1);
        while (rr) {
          int i = __builtin_ctzll(rr); rr &= rr - 1;
          float vi = rl_f(v0, i);
          float sL = vi + trs[i * U_TAGS + l];
          float sH = vi + trs[i * U_TAGS + 64 + l];
          if (sL > wL || (sL == wL && i < xL)) { wL = sL; xL = i; }
          if (sH > wH || (sH == wH && i < xH)) { wH = sH; xH = i; }
        }
        rr = rB2 & (rB2 - 1);
        while (rr) {
          int i = __builtin_ctzll(rr); rr &= rr - 1;
          float vi = rl_f(v1, i);
          float sL = vi + trs[(64 + i) * U_TAGS + l];
          float sH = vi + trs[(64 + i) * U_TAGS + 64 + l];
          if (sL > wL || (sL == wL && 64 + i < xL)) { wL = sL; xL = 64 + i; }
          if (sH > wH || (sH == wH && 64 + i < xH)) { wH = sH; xH = 64 + i; }
        }
      }

      bp[bpoff] = (unsigned char)xL;
      bp[bpoff + 64] = (unsigned char)xH;
      bpoff += U_TAGS;
      v0 = wL + lg0;  // same fp32 ops as reference
      v1 = wH + lg1;
    }

    // final argmax (first max over j=0..127)
    float val = v0; int idx = l;
    if (v1 > v0) { val = v1; idx = 64 + l; }
#pragma unroll
    for (int off = 1; off < 64; off <<= 1) {
      float vo = __shfl_xor(val, off);
      int io = __shfl_xor(idx, off);
      if (vo > val || (vo == val && io < idx)) { val = vo; idx = io; }
    }
    if (l == 0) { lastTagS = idx; tags[T_SEQ - 1] = (unsigned char)idx; }
    __builtin_amdgcn_s_setprio(0);
  } else {
    // ================= A prefetchers (waves 5..7) =================
    const int p = wv - 5;
    const float* base = x + (size_t)b * T_SEQ * D_DIM;
    for (int c = p; c < 64; c += 3) {
      while (vfl[0] < c - 6) __builtin_amdgcn_s_sleep(2);
      const float* pb = base + (size_t)c * 8 * D_DIM;
#pragma unroll
      for (int it = 0; it < 32; ++it) {
        f32x4 v = *(const f32x4*)(pb + (it * 64 + l) * 4);
        asm volatile("" ::"v"(v));  // keep load alive, discard
      }
    }
  }
  __syncthreads();  // all waves converge after the forward pass

  // Backtrack pass A: 1024 chains (8 chunks x 128 seeds), 2 per thread.
#pragma unroll
  for (int qq = 0; qq < 2; ++qq) {
    const int chain = tid + qq * 512;
    const int c = chain >> 7, s = chain & 127;
    const int lo = c * 64;
    const int hi = (c == 7) ? (T_SEQ - 2) : (c * 64 + 63);
    int cur = s;
    for (int t = hi; t >= lo; --t) cur = bp[t * U_TAGS + cur];
    M[c][s] = (unsigned char)cur;
  }
  __syncthreads();
  if (tid == 0) {
    int e = lastTagS;
    seedE[7] = (unsigned char)e;
    for (int c = 7; c >= 1; --c) { e = M[c][e]; seedE[c - 1] = (unsigned char)e; }
  }
  __syncthreads();
  if (tid < 8) {
    const int c = tid;
    const int lo = c * 64;
    const int hi = (c == 7) ? (T_SEQ - 2) : (c * 64 + 63);
    int cur = seedE[c];
    for (int t = hi; t >= lo; --t) {
      cur = bp[t * U_TAGS + cur];
      tags[t] = (unsigned char)cur;
    }
  }
  __syncthreads();
  out[(size_t)b * T_SEQ + tid] = (float)tags[tid];
}

// ---------------------------------------------------------------------------
extern "C" void kernel_launch(void* const* d_in, const int* in_sizes, int n_in,
                              void* d_out, int out_size, void* d_ws,
                              size_t ws_size, hipStream_t stream) {
  const float* x = (const float*)d_in[0];
  const float* kern = (const float*)d_in[1];
  const float* bias = (const float*)d_in[2];
  const float* chain = (const float*)d_in[3];
  const float* lb = (const float*)d_in[4];
  const float* rb = (const float*)d_in[5];
  float* out = (float*)d_out;
  (void)d_ws; (void)ws_size;  // logits never leave LDS

  crf_all<<<64, 512, 0, stream>>>(x, kern, bias, lb, rb, chain, out);
}

// Round 5
// 578.913 us; speedup vs baseline: 4.4313x; 3.1177x over previous
//
#include <hip/hip_runtime.h>

#define T_SEQ 512
#define U_TAGS 128
#define D_DIM 1024
#define M_ROWS (64 * T_SEQ)  // 32768

typedef float __attribute__((ext_vector_type(2))) f32x2;
typedef float __attribute__((ext_vector_type(4))) f32x4;

// Packed FP32 FMA (proven bitwise-exact on this harness, rounds 3/4).
//   pk_lo: d.lo += a.lo*b.lo ; d.hi += a.lo*b.hi   (broadcast a.lo)
//   pk_hi: d.lo += a.hi*b.lo ; d.hi += a.hi*b.hi   (broadcast a.hi)
__device__ __forceinline__ void pk_lo(f32x2& d, f32x2 a, f32x2 b) {
  asm("v_pk_fma_f32 %0, %1, %2, %0 op_sel:[0,0,0] op_sel_hi:[0,1,1]"
      : "+v"(d)
      : "v"(a), "v"(b));
}
__device__ __forceinline__ void pk_hi(f32x2& d, f32x2 a, f32x2 b) {
  asm("v_pk_fma_f32 %0, %1, %2, %0 op_sel:[1,0,0] op_sel_hi:[1,1,1]"
      : "+v"(d)
      : "v"(a), "v"(b));
}

// ---------------------------------------------------------------------------
// Kernel 1a: partial GEMM over half of K. Identical staging/pipeline to the
// proven 586us kernel; the 8x8 scalar micro-kernel is replaced by 32
// v_pk_fma_f32 (same k-order, IEEE-identical -> bitwise-identical output).
// VALU per wave per k halves (128->64 cy); bound moves to the LDS pipe.
// ---------------------------------------------------------------------------
__global__ __launch_bounds__(256) void crf_gemm_half(
    const float* __restrict__ A, const float* __restrict__ Bk,
    float* __restrict__ Cpart) {
  __shared__ float As[16][132];
  __shared__ float Bs[16][132];
  const int tid = threadIdx.x;
  const int tx = tid & 15, ty = tid >> 4;
  const int row0 = blockIdx.x * 128;
  const int kbase = blockIdx.y * (D_DIM / 2);

  const int am = tid >> 2, ak = (tid & 3) << 2;
  const int bk = tid >> 5, bn = (tid & 31) << 2;

  f32x2 acc[8][4] = {};  // [row][col-pair]; pair (2c,2c+1) of the 8 cols

  float4 a0 = *(const float4*)&A[(size_t)(row0 + am) * D_DIM + kbase + ak];
  float4 a1 = *(const float4*)&A[(size_t)(row0 + am + 64) * D_DIM + kbase + ak];
  float4 b0 = *(const float4*)&Bk[(size_t)(kbase + bk) * U_TAGS + bn];
  float4 b1 = *(const float4*)&Bk[(size_t)(kbase + bk + 8) * U_TAGS + bn];

  for (int k0 = 0; k0 < D_DIM / 2; k0 += 16) {
    As[ak + 0][am] = a0.x; As[ak + 1][am] = a0.y;
    As[ak + 2][am] = a0.z; As[ak + 3][am] = a0.w;
    As[ak + 0][am + 64] = a1.x; As[ak + 1][am + 64] = a1.y;
    As[ak + 2][am + 64] = a1.z; As[ak + 3][am + 64] = a1.w;
    *(float4*)&Bs[bk][bn] = b0;
    *(float4*)&Bs[bk + 8][bn] = b1;
    __syncthreads();
    if (k0 + 16 < D_DIM / 2) {
      const int kn = kbase + k0 + 16;
      a0 = *(const float4*)&A[(size_t)(row0 + am) * D_DIM + kn + ak];
      a1 = *(const float4*)&A[(size_t)(row0 + am + 64) * D_DIM + kn + ak];
      b0 = *(const float4*)&Bk[(size_t)(kn + bk) * U_TAGS + bn];
      b1 = *(const float4*)&Bk[(size_t)(kn + bk + 8) * U_TAGS + bn];
    }
#pragma unroll
    for (int kk = 0; kk < 16; ++kk) {
      const f32x4 aL = *(const f32x4*)&As[kk][ty * 8];      // rows 0..3
      const f32x4 aH = *(const f32x4*)&As[kk][ty * 8 + 4];  // rows 4..7
      const f32x4 bL = *(const f32x4*)&Bs[kk][tx * 4];      // cols 0..3
      const f32x4 bH = *(const f32x4*)&Bs[kk][tx * 4 + 64]; // cols 4..7
      const f32x2 bp0 = bL.xy, bp1 = bL.zw, bp2 = bH.xy, bp3 = bH.zw;
#pragma unroll
      for (int rp = 0; rp < 2; ++rp) {  // row pairs within aL
        const f32x2 ap = rp ? aL.zw : aL.xy;
        pk_lo(acc[rp * 2 + 0][0], ap, bp0); pk_lo(acc[rp * 2 + 0][1], ap, bp1);
        pk_lo(acc[rp * 2 + 0][2], ap, bp2); pk_lo(acc[rp * 2 + 0][3], ap, bp3);
        pk_hi(acc[rp * 2 + 1][0], ap, bp0); pk_hi(acc[rp * 2 + 1][1], ap, bp1);
        pk_hi(acc[rp * 2 + 1][2], ap, bp2); pk_hi(acc[rp * 2 + 1][3], ap, bp3);
      }
#pragma unroll
      for (int rp = 0; rp < 2; ++rp) {  // row pairs within aH
        const f32x2 ap = rp ? aH.zw : aH.xy;
        pk_lo(acc[4 + rp * 2 + 0][0], ap, bp0); pk_lo(acc[4 + rp * 2 + 0][1], ap, bp1);
        pk_lo(acc[4 + rp * 2 + 0][2], ap, bp2); pk_lo(acc[4 + rp * 2 + 0][3], ap, bp3);
        pk_hi(acc[4 + rp * 2 + 1][0], ap, bp0); pk_hi(acc[4 + rp * 2 + 1][1], ap, bp1);
        pk_hi(acc[4 + rp * 2 + 1][2], ap, bp2); pk_hi(acc[4 + rp * 2 + 1][3], ap, bp3);
      }
    }
    __syncthreads();
  }

  float* Cp = Cpart + (size_t)blockIdx.y * M_ROWS * U_TAGS;
#pragma unroll
  for (int r = 0; r < 8; ++r) {
    const int row = row0 + ty * 8 + r;
    f32x4 o0, o1;
    o0.xy = acc[r][0]; o0.zw = acc[r][1];
    o1.xy = acc[r][2]; o1.zw = acc[r][3];
    *(f32x4*)&Cp[(size_t)row * U_TAGS + tx * 4] = o0;
    *(f32x4*)&Cp[(size_t)row * U_TAGS + tx * 4 + 64] = o1;
  }
}

// ---------------------------------------------------------------------------
// Kernel 1b: logits = p0 + p1 + bias (+boundaries), in place over p0.
// (unchanged from the proven 586us kernel)
// ---------------------------------------------------------------------------
__global__ __launch_bounds__(256) void crf_combine(
    float* __restrict__ p, const float* __restrict__ bias,
    const float* __restrict__ lb, const float* __restrict__ rb) {
  const int i = blockIdx.x * 256 + threadIdx.x;  // float4 index
  const int row = i >> 5;
  const int col = (i & 31) << 2;
  const int t = row & (T_SEQ - 1);
  const float* p1 = p + (size_t)M_ROWS * U_TAGS;
  float4 v0 = *(const float4*)&p[(size_t)i * 4];
  float4 v1 = *(const float4*)&p1[(size_t)i * 4];
  float4 bb = *(const float4*)&bias[col];
  float4 o;
  o.x = v0.x + v1.x + bb.x; o.y = v0.y + v1.y + bb.y;
  o.z = v0.z + v1.z + bb.z; o.w = v0.w + v1.w + bb.w;
  if (t == 0) {
    float4 l = *(const float4*)&lb[col];
    o.x += l.x; o.y += l.y; o.z += l.z; o.w += l.w;
  }
  if (t == T_SEQ - 1) {
    float4 r = *(const float4*)&rb[col];
    o.x += r.x; o.y += r.y; o.z += r.z; o.w += r.w;
  }
  *(float4*)&p[(size_t)i * 4] = o;
}

// ---------------------------------------------------------------------------
// Fallback single-K GEMM (only if ws too small). Unchanged.
// ---------------------------------------------------------------------------
__global__ __launch_bounds__(256) void crf_gemm(
    const float* __restrict__ A, const float* __restrict__ Bk,
    const float* __restrict__ bias, const float* __restrict__ lb,
    const float* __restrict__ rb, float* __restrict__ C) {
  __shared__ float As[16][132];
  __shared__ float Bs[16][132];
  const int tid = threadIdx.x;
  const int tx = tid & 15, ty = tid >> 4;
  const int row0 = blockIdx.x * 128;
  const int am = tid >> 2, ak = (tid & 3) << 2;
  const int bk = tid >> 5, bn = (tid & 31) << 2;
  float acc[8][8] = {};
  float4 a0 = *(const float4*)&A[(size_t)(row0 + am) * D_DIM + ak];
  float4 a1 = *(const float4*)&A[(size_t)(row0 + am + 64) * D_DIM + ak];
  float4 b0 = *(const float4*)&Bk[(size_t)bk * U_TAGS + bn];
  float4 b1 = *(const float4*)&Bk[(size_t)(bk + 8) * U_TAGS + bn];
  for (int k0 = 0; k0 < D_DIM; k0 += 16) {
    As[ak + 0][am] = a0.x; As[ak + 1][am] = a0.y;
    As[ak + 2][am] = a0.z; As[ak + 3][am] = a0.w;
    As[ak + 0][am + 64] = a1.x; As[ak + 1][am + 64] = a1.y;
    As[ak + 2][am + 64] = a1.z; As[ak + 3][am + 64] = a1.w;
    *(float4*)&Bs[bk][bn] = b0;
    *(float4*)&Bs[bk + 8][bn] = b1;
    __syncthreads();
    if (k0 + 16 < D_DIM) {
      a0 = *(const float4*)&A[(size_t)(row0 + am) * D_DIM + k0 + 16 + ak];
      a1 = *(const float4*)&A[(size_t)(row0 + am + 64) * D_DIM + k0 + 16 + ak];
      b0 = *(const float4*)&Bk[(size_t)(k0 + 16 + bk) * U_TAGS + bn];
      b1 = *(const float4*)&Bk[(size_t)(k0 + 16 + bk + 8) * U_TAGS + bn];
    }
#pragma unroll
    for (int kk = 0; kk < 16; ++kk) {
      float a[8], b[8];
      *(float4*)&a[0] = *(const float4*)&As[kk][ty * 8];
      *(float4*)&a[4] = *(const float4*)&As[kk][ty * 8 + 4];
      *(float4*)&b[0] = *(const float4*)&Bs[kk][tx * 4];
      *(float4*)&b[4] = *(const float4*)&Bs[kk][tx * 4 + 64];
#pragma unroll
      for (int r = 0; r < 8; ++r)
#pragma unroll
        for (int c = 0; c < 8; ++c) acc[r][c] = fmaf(a[r], b[c], acc[r][c]);
    }
    __syncthreads();
  }
#pragma unroll
  for (int r = 0; r < 8; ++r) {
    const int row = row0 + ty * 8 + r;
    const int t = row & (T_SEQ - 1);
    const int n0 = tx * 4, n1 = tx * 4 + 64;
    float o[8];
#pragma unroll
    for (int c = 0; c < 4; ++c) {
      float v = acc[r][c] + bias[n0 + c];
      if (t == 0) v += lb[n0 + c];
      if (t == T_SEQ - 1) v += rb[n0 + c];
      o[c] = v;
    }
#pragma unroll
    for (int c = 0; c < 4; ++c) {
      float v = acc[r][c + 4] + bias[n1 + c];
      if (t == 0) v += lb[n1 + c];
      if (t == T_SEQ - 1) v += rb[n1 + c];
      o[c + 4] = v;
    }
    *(float4*)&C[(size_t)row * U_TAGS + n0] = *(float4*)&o[0];
    *(float4*)&C[(size_t)row * U_TAGS + n1] = *(float4*)&o[4];
  }
}

// ---------------------------------------------------------------------------
// Kernel 2: Viterbi, pruned, producer/consumer logit staging.
// (byte-identical to the proven 586us kernel)
// ---------------------------------------------------------------------------
__device__ __forceinline__ float rl_f(float v, int lane) {
  return __int_as_float(__builtin_amdgcn_readlane(__float_as_int(v), lane));
}
template <int CTRL>
__device__ __forceinline__ float dpp_max_step(float x) {
  int v = __float_as_int(x);
  int t = __builtin_amdgcn_update_dpp(v, v, CTRL, 0xF, 0xF, false);
  return fmaxf(x, __int_as_float(t));
}
__device__ __forceinline__ float wave_max64_bcast(float x) {
  x = dpp_max_step<0x111>(x);  // row_shr:1
  x = dpp_max_step<0x112>(x);  // row_shr:2
  x = dpp_max_step<0x114>(x);  // row_shr:4
  x = dpp_max_step<0x118>(x);  // row_shr:8
  x = dpp_max_step<0x142>(x);  // row_bcast:15
  x = dpp_max_step<0x143>(x);  // row_bcast:31
  return rl_f(x, 63);
}
// keep a on ties; a must carry the smaller candidate index
__device__ __forceinline__ void win(float sa, int ia, float sb, int ib,
                                    float& so, int& io) {
  bool g = sa >= sb;
  so = g ? sa : sb;
  io = g ? ia : ib;
}

__global__ __launch_bounds__(256) void crf_viterbi(
    const float* __restrict__ logits,  // [64, 512, 128]
    const float* __restrict__ trans,   // [128, 128]
    float* __restrict__ out) {         // [64, 512] fp32 tags
  __shared__ __align__(16) float trs[U_TAGS * U_TAGS];              // 64 KB
  __shared__ __align__(16) unsigned char bp[(T_SEQ - 1) * U_TAGS];  // 65408 B
  __shared__ __align__(16) float ring[4 * 8 * U_TAGS];              // 16 KB
  __shared__ int flags[2];  // [0]=chunks produced, [1]=chunks consumed
  __shared__ unsigned char tags[T_SEQ];
  __shared__ unsigned char M[8][U_TAGS];
  __shared__ unsigned char seedE[8];
  __shared__ float rmaxs[U_TAGS];
  __shared__ float wmin2[2];
  __shared__ float gminS;
  __shared__ int lastTagS;

  const int b = blockIdx.x;
  const int tid = threadIdx.x;
  const float* lg_b = logits + (size_t)b * T_SEQ * U_TAGS;

  // Stage trans (coalesced), 16 float4 per thread.
#pragma unroll
  for (int it = 0; it < 16; ++it)
    *(float4*)&trs[(it * 256 + tid) * 4] =
        *(const float4*)&trans[(it * 256 + tid) * 4];
  if (tid == 0) { flags[0] = 0; flags[1] = 0; }
  __syncthreads();

  // rmaxs[i] = max_j trs[i][j]; gmin = min over all trans.
  float rowmin = 1e30f;
  if (tid < U_TAGS) {
    float mx = -1e30f, mn = 1e30f;
    for (int q = 0; q < 32; ++q) {
      float4 v = *(const float4*)&trs[tid * U_TAGS + q * 4];
      mx = fmaxf(fmaxf(mx, v.x), fmaxf(v.y, fmaxf(v.z, v.w)));
      mn = fminf(fminf(mn, v.x), fminf(v.y, fminf(v.z, v.w)));
    }
    rmaxs[tid] = mx;
    rowmin = mn;
#pragma unroll
    for (int off = 1; off < 64; off <<= 1)
      rowmin = fminf(rowmin, __shfl_xor(rowmin, off));
    if ((tid & 63) == 0) wmin2[tid >> 6] = rowmin;
  }
  __syncthreads();
  if (tid == 0) gminS = fminf(wmin2[0], wmin2[1]);
  __syncthreads();

  const int wv = tid >> 6, l = tid & 63;
  volatile int* vfl = (volatile int*)flags;

  if (wv == 1) {
    // ---- producer: 64 chunks x (8 steps x 128 floats = 4 KB) ----
    const float4* src = (const float4*)lg_b;
    float4* dst = (float4*)ring;
    for (int c = 0; c < 64; ++c) {
      while (vfl[1] + 4 <= c) { }  // ring credit
      const float4* s4 = src + c * 256;
      float4 d0 = s4[l], d1 = s4[l + 64], d2 = s4[l + 128], d3 = s4[l + 192];
      float4* d4 = dst + (c & 3) * 256;
      d4[l] = d0; d4[l + 64] = d1; d4[l + 128] = d2; d4[l + 192] = d3;
      __threadfence_block();
      if (l == 0) vfl[0] = c + 1;
    }
  } else if (wv == 0) {
    // ---- consumer: the whole forward recurrence, LDS-only ----
    const float cc0 = rmaxs[l] - gminS + 0.01f;
    const float cc1 = rmaxs[64 + l] - gminS + 0.01f;
    while (vfl[0] < 1) { }
    float v0 = ring[l];       // t=0 (lb fused upstream)
    float v1 = ring[64 + l];
    const unsigned long long G = 0x8000000000000000ull;
    int bpoff = l;

    for (int t = 1; t < T_SEQ; ++t) {
      if ((t & 7) == 0) {
        const int c = t >> 3;
        if (l == 0) vfl[1] = c;       // chunks < c fully consumed
        while (vfl[0] <= c) { }
      }
      const float* sl = ring + ((t >> 3) & 3) * 1024 + (t & 7) * U_TAGS;
      float lg0 = sl[l];
      float lg1 = sl[64 + l];

      const float vm = wave_max64_bcast(fmaxf(v0, v1));
      unsigned long long m0 = __ballot(v0 + cc0 >= vm);
      unsigned long long m1 = __ballot(v1 + cc1 >= vm);

      // 3 slots per half; empty/dup -> guard index 63 (a real pair).
      unsigned long long rA1 = m0 & (m0 - 1), rA2 = rA1 & (rA1 - 1);
      unsigned long long rB1 = m1 & (m1 - 1), rB2 = rB1 & (rB1 - 1);
      const int iA0 = __builtin_ctzll(m0 | G);
      const int iA1 = __builtin_ctzll(rA1 | G);
      const int iA2 = __builtin_ctzll(rA2 | G);
      const int iB0 = __builtin_ctzll(m1 | G);
      const int iB1 = __builtin_ctzll(rB1 | G);
      const int iB2 = __builtin_ctzll(rB2 | G);
      unsigned long long tail = (rA2 & (rA2 - 1)) | (rB2 & (rB2 - 1));

      const float svA0 = rl_f(v0, iA0), svA1 = rl_f(v0, iA1),
                  svA2 = rl_f(v0, iA2);
      const float svB0 = rl_f(v1, iB0), svB1 = rl_f(v1, iB1),
                  svB2 = rl_f(v1, iB2);

      const float* pA0 = &trs[iA0 * U_TAGS + l];
      const float* pA1 = &trs[iA1 * U_TAGS + l];
      const float* pA2 = &trs[iA2 * U_TAGS + l];
      const float* pB0 = &trs[(64 + iB0) * U_TAGS + l];
      const float* pB1 = &trs[(64 + iB1) * U_TAGS + l];
      const float* pB2 = &trs[(64 + iB2) * U_TAGS + l];
      const float tA0L = pA0[0], tA0H = pA0[64];
      const float tA1L = pA1[0], tA1H = pA1[64];
      const float tA2L = pA2[0], tA2H = pA2[64];
      const float tB0L = pB0[0], tB0H = pB0[64];
      const float tB1L = pB1[0], tB1H = pB1[64];
      const float tB2L = pB2[0], tB2H = pB2[64];

      // L target (j = l)
      float wa, wb, wL; int xa, xb, xL;
      win(svA0 + tA0L, iA0, svA1 + tA1L, iA1, wa, xa);
      win(wa, xa, svA2 + tA2L, iA2, wa, xa);
      win(svB0 + tB0L, 64 + iB0, svB1 + tB1L, 64 + iB1, wb, xb);
      win(wb, xb, svB2 + tB2L, 64 + iB2, wb, xb);
      win(wa, xa, wb, xb, wL, xL);
      // H target (j = 64 + l)
      float wH; int xH;
      win(svA0 + tA0H, iA0, svA1 + tA1H, iA1, wa, xa);
      win(wa, xa, svA2 + tA2H, iA2, wa, xa);
      win(svB0 + tB0H, 64 + iB0, svB1 + tB1H, 64 + iB1, wb, xb);
      win(wb, xb, svB2 + tB2H, 64 + iB2, wb, xb);
      win(wa, xa, wb, xb, wH, xH);

      if (tail) {  // rare: >3 candidates in a half, tie-aware
        unsigned long long r = rA2 & (rA2 - 1);
        while (r) {
          int i = __builtin_ctzll(r); r &= r - 1;
          float vi = rl_f(v0, i);
          float sL = vi + trs[i * U_TAGS + l];
          float sH = vi + trs[i * U_TAGS + 64 + l];
          if (sL > wL || (sL == wL && i < xL)) { wL = sL; xL = i; }
          if (sH > wH || (sH == wH && i < xH)) { wH = sH; xH = i; }
        }
        r = rB2 & (rB2 - 1);
        while (r) {
          int i = __builtin_ctzll(r); r &= r - 1;
          float vi = rl_f(v1, i);
          float sL = vi + trs[(64 + i) * U_TAGS + l];
          float sH = vi + trs[(64 + i) * U_TAGS + 64 + l];
          if (sL > wL || (sL == wL && 64 + i < xL)) { wL = sL; xL = 64 + i; }
          if (sH > wH || (sH == wH && 64 + i < xH)) { wH = sH; xH = 64 + i; }
        }
      }

      bp[bpoff] = (unsigned char)xL;
      bp[bpoff + 64] = (unsigned char)xH;
      bpoff += U_TAGS;
      v0 = wL + lg0;  // same fp32 ops as reference
      v1 = wH + lg1;
    }

    // final argmax (first max over j=0..127)
    float val = v0; int idx = l;
    if (v1 > v0) { val = v1; idx = 64 + l; }
#pragma unroll
    for (int off = 1; off < 64; off <<= 1) {
      float vo = __shfl_xor(val, off);
      int io = __shfl_xor(idx, off);
      if (vo > val || (vo == val && io < idx)) { val = vo; idx = io; }
    }
    if (l == 0) { lastTagS = idx; tags[T_SEQ - 1] = (unsigned char)idx; }
  }
  __syncthreads();  // waves 2-3 waited here during the forward pass

  // Backtrack pass A: 1024 chains (8 chunks x 128 seeds), 4 per thread.
#pragma unroll
  for (int q = 0; q < 4; ++q) {
    const int chain = tid + q * 256;
    const int c = chain >> 7, s = chain & 127;
    const int lo = c * 64;
    const int hi = (c == 7) ? (T_SEQ - 2) : (c * 64 + 63);
    int cur = s;
    for (int t = hi; t >= lo; --t) cur = bp[t * U_TAGS + cur];
    M[c][s] = (unsigned char)cur;
  }
  __syncthreads();
  if (tid == 0) {
    int e = lastTagS;
    seedE[7] = (unsigned char)e;
    for (int c = 7; c >= 1; --c) { e = M[c][e]; seedE[c - 1] = (unsigned char)e; }
  }
  __syncthreads();
  if (tid < 8) {
    const int c = tid;
    const int lo = c * 64;
    const int hi = (c == 7) ? (T_SEQ - 2) : (c * 64 + 63);
    int cur = seedE[c];
    for (int t = hi; t >= lo; --t) {
      cur = bp[t * U_TAGS + cur];
      tags[t] = (unsigned char)cur;
    }
  }
  __syncthreads();
  out[(size_t)b * T_SEQ + tid] = (float)tags[tid];
  out[(size_t)b * T_SEQ + 256 + tid] = (float)tags[256 + tid];
}

// ---------------------------------------------------------------------------
extern "C" void kernel_launch(void* const* d_in, const int* in_sizes, int n_in,
                              void* d_out, int out_size, void* d_ws,
                              size_t ws_size, hipStream_t stream) {
  const float* x = (const float*)d_in[0];
  const float* kern = (const float*)d_in[1];
  const float* bias = (const float*)d_in[2];
  const float* chain = (const float*)d_in[3];
  const float* lb = (const float*)d_in[4];
  const float* rb = (const float*)d_in[5];
  float* out = (float*)d_out;
  float* logits = (float*)d_ws;  // final logits at ws base in all paths

  const size_t part = (size_t)M_ROWS * U_TAGS * sizeof(float);  // 16.8 MB
  if (ws_size >= 2 * part) {
    crf_gemm_half<<<dim3(256, 2), 256, 0, stream>>>(x, kern, logits);
    crf_combine<<<(M_ROWS * U_TAGS / 4 + 255) / 256, 256, 0, stream>>>(
        logits, bias, lb, rb);
  } else {
    crf_gemm<<<256, 256, 0, stream>>>(x, kern, bias, lb, rb, logits);
  }
  crf_viterbi<<<64, 256, 0, stream>>>(logits, chain, out);
}